// Round 5
// baseline (221.478 us; speedup 1.0000x reference)
//
#include <hip/hip_runtime.h>
#include <hip/hip_bf16.h>

// CapsuleLayer routing via bf16 MFMA, fused pipeline. B=512,P=1152,N=10,T=16,D=8.
// GEMM1 (s-pass): s[b,nt] = sum_k Xb[b,k]*Wc[nt,k], k=(p,d), K=9216 — fused with
//   split-K LDS reduce + squash -> writes Vt bf16 (iters 0,1) / d_out fp32 (iter 2).
// GEMM2 (agreement): H[pd,nt] = sum_b Xt[pd,b]*Vt[nt,b] — fused with the W
//   contraction -> bbar[p,n] += mean agreement (2 p per block, no Ht buffer).
// Layout facts verified by round-4 pass: A: m=lane&15,k=q*8+j; B: n=lane&15,
// k=q*8+j; D: col=lane&15, row=q*4+reg  (16x16x32 bf16 MFMA).

typedef __attribute__((ext_vector_type(8))) short bfrag;   // 8 bf16 (4 VGPR)
typedef __attribute__((ext_vector_type(4))) float f32x4;

constexpr int B_ = 512, P_ = 1152, N_ = 10, T_ = 16, D_ = 8;
constexpr int NT_ = 160;
constexpr int K1_ = P_ * D_;            // 9216
constexpr int NKC_ = K1_ / 32;          // 288 k-chunks

__device__ __forceinline__ unsigned short f2bf(float f) {
    unsigned u = __float_as_uint(f);
    unsigned r = (u + 0x7fffu + ((u >> 16) & 1u)) >> 16;   // round-nearest-even
    return (unsigned short)r;
}

// ---- one-time: x fp32 -> Xb bf16 [b][pd] AND Xt bf16 [pd][b] ---------------
__global__ __launch_bounds__(256) void k_xbt(const float* __restrict__ x,
                                             unsigned short* __restrict__ Xb,
                                             unsigned short* __restrict__ Xt) {
    __shared__ unsigned short tile[64][72];
    const int pd0 = blockIdx.x * 64, b0 = blockIdx.y * 64;
    const int c0 = threadIdx.x & 63, r0 = threadIdx.x >> 6;
#pragma unroll
    for (int i = 0; i < 16; ++i) {
        const int br = r0 + i * 4;
        const unsigned short v = f2bf(x[(size_t)(b0 + br) * K1_ + pd0 + c0]);
        tile[c0][br] = v;
        Xb[(size_t)(b0 + br) * K1_ + pd0 + c0] = v;
    }
    __syncthreads();
#pragma unroll
    for (int i = 0; i < 16; ++i) {
        const int pr = r0 + i * 4;
        Xt[(size_t)(pd0 + pr) * B_ + b0 + c0] = tile[pr][c0];
    }
}

// ---- per-iter: Wc[kc][nt][32] bf16 = softmax(bbar)[p,n] * W[p,nt,d] --------
__global__ __launch_bounds__(256) void k_wc(const float* __restrict__ W,
                                            const float* __restrict__ bbar,
                                            unsigned short* __restrict__ Wc) {
    const int idx = blockIdx.x * 256 + threadIdx.x;    // 184320 = 720 blocks
    const int p = idx / NT_, nt = idx % NT_, n = nt >> 4;
    const float* br = bbar + (size_t)p * N_;
    float bv[N_], m = -1e30f;
#pragma unroll
    for (int k = 0; k < N_; ++k) { bv[k] = br[k]; m = fmaxf(m, bv[k]); }
    float sum = 0.f;
#pragma unroll
    for (int k = 0; k < N_; ++k) { bv[k] = __expf(bv[k] - m); sum += bv[k]; }
    const float c = bv[n] / sum;
    const float* wr = W + (size_t)idx * D_;
    f32x4 a = *(const f32x4*)wr;
    f32x4 b = *(const f32x4*)(wr + 4);
    unsigned w0 = f2bf(c * a.x) | ((unsigned)f2bf(c * a.y) << 16);
    unsigned w1 = f2bf(c * a.z) | ((unsigned)f2bf(c * a.w) << 16);
    unsigned w2 = f2bf(c * b.x) | ((unsigned)f2bf(c * b.y) << 16);
    unsigned w3 = f2bf(c * b.z) | ((unsigned)f2bf(c * b.w) << 16);
    uint4 v = make_uint4(w0, w1, w2, w3);
    *(uint4*)(Wc + (size_t)(p >> 2) * 5120 + nt * 32 + (p & 3) * 8) = v;
}

// ---- GEMM1 + split-K reduce + squash. grid (32,5), 256 thr = 4 waves -------
// block tile: 16 b x 32 nt (2 n). wave w: K-chunks [72w, 72w+72).
__global__ __launch_bounds__(256) void k_sv(const unsigned short* __restrict__ Xb,
                                            const unsigned short* __restrict__ Wc,
                                            unsigned short* __restrict__ Vt,
                                            float* __restrict__ outp,
                                            int final_it) {
    __shared__ float red[3 * 512];
    const int tid = threadIdx.x;
    const int w = tid >> 6, lane = tid & 63;
    const int col = lane & 15, q = lane >> 4;
    const int m0 = blockIdx.x * 16;
    const int n0 = blockIdx.y * 2;

    f32x4 acc[2];
    acc[0] = (f32x4){0.f, 0.f, 0.f, 0.f};
    acc[1] = (f32x4){0.f, 0.f, 0.f, 0.f};

    const int kc0 = w * (NKC_ / 4);
    for (int kc = kc0; kc < kc0 + NKC_ / 4; ++kc) {
        bfrag a = *(const bfrag*)(Xb + (size_t)(m0 + col) * K1_ + kc * 32 + q * 8);
#pragma unroll
        for (int jn = 0; jn < 2; ++jn) {
            bfrag b = *(const bfrag*)(Wc + (size_t)kc * 5120 + ((n0 + jn) * 16 + col) * 32 + q * 8);
            acc[jn] = __builtin_amdgcn_mfma_f32_16x16x32_bf16(a, b, acc[jn], 0, 0, 0);
        }
    }
    if (w) {
#pragma unroll
        for (int jn = 0; jn < 2; ++jn)
#pragma unroll
            for (int r = 0; r < 4; ++r)
                red[(w - 1) * 512 + jn * 256 + r * 64 + q * 16 + col] = acc[jn][r];
    }
    __syncthreads();
    if (w == 0) {
#pragma unroll
        for (int jn = 0; jn < 2; ++jn) {
#pragma unroll
            for (int r = 0; r < 4; ++r) {
                const int li = jn * 256 + r * 64 + q * 16 + col;
                float s = acc[jn][r] + red[li] + red[512 + li] + red[1024 + li];
                float sq = s * s;
                sq += __shfl_xor(sq, 1);
                sq += __shfl_xor(sq, 2);
                sq += __shfl_xor(sq, 4);
                sq += __shfl_xor(sq, 8);
                const float norm = sqrtf(sq);
                const float scale = sq / (1.0f + sq * (norm + 1e-9f));
                const float vv = s * scale;
                const int b = m0 + q * 4 + r;
                const int nt = (n0 + jn) * 16 + col;
                if (final_it) outp[(size_t)b * NT_ + nt] = vv;
                else          Vt[(size_t)nt * B_ + b] = f2bf(vv);
            }
        }
    }
}

// ---- GEMM2 + contraction: bbar[p,n] += (1/B) sum_{d,t} W * H. grid 576x64 --
// H[pd,nt] = sum_b Vt[nt,b]*Xt[pd,b]; D-tile: lane col = pd offset, rows = nt.
__global__ __launch_bounds__(64) void k_ga(const unsigned short* __restrict__ Vt,
                                           const unsigned short* __restrict__ Xt,
                                           const float* __restrict__ W,
                                           float* __restrict__ bbar) {
    const int lane = threadIdx.x;
    const int col = lane & 15, q = lane >> 4;
    const int pd0 = blockIdx.x * 16;
    f32x4 acc[10];
#pragma unroll
    for (int mt = 0; mt < 10; ++mt) acc[mt] = (f32x4){0.f, 0.f, 0.f, 0.f};

    for (int kc = 0; kc < B_ / 32; ++kc) {
        bfrag bf = *(const bfrag*)(Xt + (size_t)(pd0 + col) * B_ + kc * 32 + q * 8);
#pragma unroll
        for (int mt = 0; mt < 10; ++mt) {
            bfrag af = *(const bfrag*)(Vt + (size_t)(mt * 16 + col) * B_ + kc * 32 + q * 8);
            acc[mt] = __builtin_amdgcn_mfma_f32_16x16x32_bf16(af, bf, acc[mt], 0, 0, 0);
        }
    }
    // lane owns pd = pd0+col -> p = pd>>3, d = col&7; rows nt = mt*16 + q*4 + r
    const int p = (pd0 + col) >> 3, d = col & 7;
    float part[10];
#pragma unroll
    for (int mt = 0; mt < 10; ++mt) {
        float s = 0.f;
#pragma unroll
        for (int r = 0; r < 4; ++r)
            s = fmaf(W[((size_t)p * NT_ + mt * 16 + q * 4 + r) * D_ + d], acc[mt][r], s);
        s += __shfl_xor(s, 1);    // reduce over d
        s += __shfl_xor(s, 2);
        s += __shfl_xor(s, 4);
        s += __shfl_xor(s, 16);   // reduce over q (t-quarters)
        s += __shfl_xor(s, 32);
        part[mt] = s;
    }
    if (q == 0 && d == 0) {       // lanes 0 (p even) and 8 (p odd)
#pragma unroll
        for (int mt = 0; mt < 10; ++mt)
            bbar[(size_t)p * N_ + mt] += part[mt] * (1.0f / 512.0f);
    }
}

extern "C" void kernel_launch(void* const* d_in, const int* in_sizes, int n_in,
                              void* d_out, int out_size, void* d_ws, size_t ws_size,
                              hipStream_t stream) {
    const float* x = (const float*)d_in[0];   // fp32 [B][P*D]
    const float* W = (const float*)d_in[1];   // fp32 [P][NT][D]

    char* wsp = (char*)d_ws;
    float* bbar = (float*)wsp;                                  // 46080 B
    unsigned short* Xb = (unsigned short*)(wsp + 46080);        // 9.44 MB
    unsigned short* Xt = Xb + (size_t)B_ * K1_;                 // 9.44 MB
    unsigned short* Wc = Xt + (size_t)B_ * K1_;                 // 2.95 MB
    unsigned short* Vt = Wc + (size_t)NKC_ * 5120;              // 160 KB  (~22 MB total)

    hipMemsetAsync(bbar, 0, (size_t)P_ * N_ * sizeof(float), stream);
    k_xbt<<<dim3(K1_ / 64, B_ / 64), dim3(256), 0, stream>>>(x, Xb, Xt);

    for (int it = 0; it < 3; ++it) {
        k_wc<<<dim3(720), dim3(256), 0, stream>>>(W, bbar, Wc);
        k_sv<<<dim3(32, 5), dim3(256), 0, stream>>>(Xb, Wc, Vt, (float*)d_out, it == 2);
        if (it < 2)
            k_ga<<<dim3(576), dim3(64), 0, stream>>>(Vt, Xt, W, bbar);
    }
}

// Round 7
// 191.814 us; speedup vs baseline: 1.1546x; 1.1546x over previous
//
#include <hip/hip_runtime.h>
#include <hip/hip_bf16.h>

// CapsuleLayer routing, bf16 MFMA, 6 plain dispatches (coop launch fails in
// this harness). B=512,P=1152,N=10,T=16,D=8, 3 iters.
// Verified 16x16x32 bf16 MFMA layouts (rounds 4-5 passing):
//   A: m=lane&15, k=q*8+j   B: n=lane&15, k=q*8+j   D: col=lane&15, row=q*4+r
// GEMM1 (k_sv): s[b,nt] = sum_{p,d} x[b,pd] * (c[p,n] W[p,nt,d]), K=9216.
//   A- and B-fragments built on the fly from fp32 x and W (x is bf16-exact ->
//   conversion bit-identical to a precomputed Xb). Per-block softmax in LDS.
//   8-wave split-K + LDS reduce + fused squash -> Vt bf16 / d_out fp32.
// GEMM2 (k_ga): H[pd,nt] = sum_b Xt[pd,b] Vt[nt,b], fused W-contraction ->
//   bbar (store on iter 0, accumulate on iter 1). No memsets anywhere.

typedef __attribute__((ext_vector_type(8))) short bfrag;   // 8 bf16
typedef __attribute__((ext_vector_type(4))) float f32x4;

constexpr int B_ = 512, P_ = 1152, N_ = 10, NT_ = 160;
constexpr int K1_ = P_ * 8;        // 9216
constexpr int NKC_ = K1_ / 32;     // 288 k-chunks

__device__ __forceinline__ unsigned short f2bf(float f) {
    unsigned u = __float_as_uint(f);
    return (unsigned short)((u + 0x7fffu + ((u >> 16) & 1u)) >> 16);  // RNE
}

__device__ __forceinline__ bfrag mkfrag(f32x4 a, f32x4 b, float c) {
    bfrag f;
    f[0] = (short)f2bf(a.x * c); f[1] = (short)f2bf(a.y * c);
    f[2] = (short)f2bf(a.z * c); f[3] = (short)f2bf(a.w * c);
    f[4] = (short)f2bf(b.x * c); f[5] = (short)f2bf(b.y * c);
    f[6] = (short)f2bf(b.z * c); f[7] = (short)f2bf(b.w * c);
    return f;
}

// ---- one-time: Xt[pd][b] bf16 transpose of x (validated r4/r5 structure) ---
__global__ __launch_bounds__(256) void k_xt(const float* __restrict__ x,
                                            unsigned short* __restrict__ Xt) {
    __shared__ unsigned short tile[64][72];
    const int pd0 = blockIdx.x * 64, b0 = blockIdx.y * 64;
    const int c0 = threadIdx.x & 63, r0 = threadIdx.x >> 6;
#pragma unroll
    for (int i = 0; i < 16; ++i) {
        const int br = r0 + i * 4;
        tile[c0][br] = f2bf(x[(size_t)(b0 + br) * K1_ + pd0 + c0]);
    }
    __syncthreads();
#pragma unroll
    for (int i = 0; i < 16; ++i) {
        const int pr = r0 + i * 4;
        Xt[(size_t)(pd0 + pr) * B_ + b0 + c0] = tile[pr][c0];
    }
}

// ---- GEMM1 + squash. grid (32,5), 512 thr = 8 waves, 36 K-chunks/wave ------
// mode 0: c = 0.1 (iter 0, bbar unread). mode 1: softmax(bbar) per block.
// mode 2: final iter, write d_out fp32.
__global__ __launch_bounds__(512) void k_sv(const float* __restrict__ x,
                                            const float* __restrict__ W,
                                            const float* __restrict__ bbar,
                                            unsigned short* __restrict__ Vt,
                                            float* __restrict__ outp,
                                            int mode) {
    __shared__ float csA[P_], csB[P_];
    __shared__ float red[7 * 512];
    const int tid = threadIdx.x;
    const int w = tid >> 6, lane = tid & 63, col = lane & 15, q = lane >> 4;
    const int m0 = blockIdx.x * 16;     // 16 b-rows
    const int n0 = blockIdx.y * 2;      // 2 n per block

    if (mode) {
        for (int idx = tid; idx < P_; idx += 512) {
            const float* br = bbar + (size_t)idx * N_;
            float bv[N_], m = -1e30f;
#pragma unroll
            for (int n = 0; n < N_; ++n) { bv[n] = br[n]; m = fmaxf(m, bv[n]); }
            float sum = 0.f;
#pragma unroll
            for (int n = 0; n < N_; ++n) { bv[n] = __expf(bv[n] - m); sum += bv[n]; }
            const float inv = 1.f / sum;
            csA[idx] = bv[n0] * inv;
            csB[idx] = bv[n0 + 1] * inv;
        }
        __syncthreads();
    }

    f32x4 acc0 = (f32x4){0.f, 0.f, 0.f, 0.f};
    f32x4 acc1 = (f32x4){0.f, 0.f, 0.f, 0.f};
    const int kc0 = w * (NKC_ / 8);     // 36 chunks per wave
    for (int kc = kc0; kc < kc0 + NKC_ / 8; ++kc) {
        const float* xr = x + (size_t)(m0 + col) * K1_ + kc * 32 + q * 8;
        const bfrag a = mkfrag(*(const f32x4*)xr, *(const f32x4*)(xr + 4), 1.0f);
        const int p = kc * 4 + q;
        const float* wr = W + ((size_t)p * NT_ + n0 * 16 + col) * 8;
        const f32x4 wa0 = *(const f32x4*)wr;
        const f32x4 wb0 = *(const f32x4*)(wr + 4);
        const f32x4 wa1 = *(const f32x4*)(wr + 128);   // next n = +16 rows
        const f32x4 wb1 = *(const f32x4*)(wr + 132);
        const float cA = mode ? csA[p] : 0.1f;
        const float cB = mode ? csB[p] : 0.1f;
        acc0 = __builtin_amdgcn_mfma_f32_16x16x32_bf16(a, mkfrag(wa0, wb0, cA), acc0, 0, 0, 0);
        acc1 = __builtin_amdgcn_mfma_f32_16x16x32_bf16(a, mkfrag(wa1, wb1, cB), acc1, 0, 0, 0);
    }
    if (w) {
#pragma unroll
        for (int r = 0; r < 4; ++r) {
            red[(w - 1) * 512 + r * 64 + q * 16 + col] = acc0[r];
            red[(w - 1) * 512 + 256 + r * 64 + q * 16 + col] = acc1[r];
        }
    }
    __syncthreads();
    if (w == 0) {
#pragma unroll
        for (int jn = 0; jn < 2; ++jn) {
#pragma unroll
            for (int r = 0; r < 4; ++r) {
                const int li = jn * 256 + r * 64 + q * 16 + col;
                float s = jn ? acc1[r] : acc0[r];
#pragma unroll
                for (int j = 0; j < 7; ++j) s += red[j * 512 + li];
                float sq = s * s;                      // t = col (16 lanes)
                sq += __shfl_xor(sq, 1);
                sq += __shfl_xor(sq, 2);
                sq += __shfl_xor(sq, 4);
                sq += __shfl_xor(sq, 8);
                const float norm = sqrtf(sq);
                const float scale = sq / (1.0f + sq * (norm + 1e-9f));
                const float vv = s * scale;
                const int b = m0 + q * 4 + r;
                const int nt = (n0 + jn) * 16 + col;
                if (mode == 2) outp[(size_t)b * NT_ + nt] = vv;
                else           Vt[(size_t)nt * B_ + b] = f2bf(vv);
            }
        }
    }
}

// ---- GEMM2 + W-contraction (validated r5 body + store/accum flag) ----------
// grid 576, 64 thr. H-tile D-layout: col = pd offset, rows = nt = mt*16+q*4+r.
__global__ __launch_bounds__(64) void k_ga(const unsigned short* __restrict__ Vt,
                                           const unsigned short* __restrict__ Xt,
                                           const float* __restrict__ W,
                                           float* __restrict__ bbar,
                                           int accum) {
    const int lane = threadIdx.x;
    const int col = lane & 15, q = lane >> 4;
    const int pd0 = blockIdx.x * 16;
    f32x4 acc[N_];
#pragma unroll
    for (int mt = 0; mt < N_; ++mt) acc[mt] = (f32x4){0.f, 0.f, 0.f, 0.f};

    for (int kc = 0; kc < B_ / 32; ++kc) {
        const bfrag bf = *(const bfrag*)(Xt + (size_t)(pd0 + col) * B_ + kc * 32 + q * 8);
#pragma unroll
        for (int mt = 0; mt < N_; ++mt) {
            const bfrag af = *(const bfrag*)(Vt + (size_t)(mt * 16 + col) * B_ + kc * 32 + q * 8);
            acc[mt] = __builtin_amdgcn_mfma_f32_16x16x32_bf16(af, bf, acc[mt], 0, 0, 0);
        }
    }
    const int p = (pd0 + col) >> 3, d = col & 7;
    float part[N_];
#pragma unroll
    for (int mt = 0; mt < N_; ++mt) {
        float s = 0.f;
#pragma unroll
        for (int r = 0; r < 4; ++r)
            s = fmaf(W[((size_t)p * NT_ + mt * 16 + q * 4 + r) * 8 + d], acc[mt][r], s);
        s += __shfl_xor(s, 1);    // reduce over d
        s += __shfl_xor(s, 2);
        s += __shfl_xor(s, 4);
        s += __shfl_xor(s, 16);   // reduce over t-quarters
        s += __shfl_xor(s, 32);
        part[mt] = s;
    }
    if (q == 0 && d == 0) {       // lanes 0 and 8: the 2 p's of this tile
#pragma unroll
        for (int mt = 0; mt < N_; ++mt) {
            const float val = part[mt] * (1.0f / 512.0f);
            float* dst = bbar + (size_t)p * N_ + mt;
            *dst = accum ? (*dst + val) : val;
        }
    }
}

extern "C" void kernel_launch(void* const* d_in, const int* in_sizes, int n_in,
                              void* d_out, int out_size, void* d_ws, size_t ws_size,
                              hipStream_t stream) {
    const float* x = (const float*)d_in[0];   // fp32 [B][P*D]
    const float* W = (const float*)d_in[1];   // fp32 [P][NT][D]

    char* wsp = (char*)d_ws;
    float* bbar = (float*)wsp;                                  // 46080 B
    unsigned short* Xt = (unsigned short*)(wsp + 46080);        // 9.44 MB
    unsigned short* Vt = Xt + (size_t)B_ * K1_;                 // 160 KB
    float* outp = (float*)d_out;

    k_xt<<<dim3(K1_ / 64, B_ / 64), dim3(256), 0, stream>>>(x, Xt);
    k_sv<<<dim3(32, 5), dim3(512), 0, stream>>>(x, W, bbar, Vt, outp, 0);
    k_ga<<<dim3(576), dim3(64), 0, stream>>>(Vt, Xt, W, bbar, 0);
    k_sv<<<dim3(32, 5), dim3(512), 0, stream>>>(x, W, bbar, Vt, outp, 1);
    k_ga<<<dim3(576), dim3(64), 0, stream>>>(Vt, Xt, W, bbar, 1);
    k_sv<<<dim3(32, 5), dim3(512), 0, stream>>>(x, W, bbar, Vt, outp, 2);
}